// Round 5
// baseline (157.024 us; speedup 1.0000x reference)
//
#include <hip/hip_runtime.h>
#include <hip/hip_bf16.h>

#define DI __device__ __forceinline__

using f32x4  = __attribute__((ext_vector_type(4)))  float;
using f32x16 = __attribute__((ext_vector_type(16))) float;
using s16x8  = __attribute__((ext_vector_type(8)))  short;
using s32x4  = __attribute__((ext_vector_type(4)))  int;
using u16x4  = __attribute__((ext_vector_type(4)))  unsigned short;
using u32x4  = __attribute__((ext_vector_type(4)))  unsigned;

typedef __attribute__((address_space(3))) unsigned       lds_u32;
typedef __attribute__((address_space(3))) unsigned short lds_u16;
typedef const __attribute__((address_space(1))) unsigned ga_u32;

DI unsigned short f2bf(float f) {
  union { float f; unsigned u; } v; v.f = f;
  unsigned r = v.u + 0x7FFFu + ((v.u >> 16) & 1u);   // RNE
  return (unsigned short)(r >> 16);
}

DI unsigned cvtpk(float lo, float hi) {
  unsigned d;
  asm("v_cvt_pk_bf16_f32 %0, %1, %2" : "=v"(d) : "v"(lo), "v"(hi));
  return d;
}
DI void pswap(unsigned &a, unsigned &b) {
  asm("v_permlane32_swap_b32 %0, %1" : "+v"(a), "+v"(b));
}

// Q scale: 1/sqrt(64) * log2(e)  (scores in log2 domain -> exp2 in attn)
#define QSCALE 0.18033688011112042f

// ---------------- fused prep ----------------
__global__ void k_prep(const float* __restrict__ x, const float* __restrict__ wq,
                       const float* __restrict__ wk, const float* __restrict__ wv,
                       const float* __restrict__ wo, unsigned short* __restrict__ xb,
                       unsigned short* __restrict__ Wt, unsigned short* __restrict__ Wot) {
  int bid = blockIdx.x;
  if (bid < 4096) {                                  // x convert, vec4
    int i = (bid * 256 + threadIdx.x) * 4;
    f32x4 v = *reinterpret_cast<const f32x4*>(x + i);
    u16x4 o;
    o[0] = f2bf(v[0]); o[1] = f2bf(v[1]); o[2] = f2bf(v[2]); o[3] = f2bf(v[3]);
    *reinterpret_cast<u16x4*>(xb + i) = o;
  } else if (bid < 16384) {                          // Wt (transpose h<->k)
    int o = (bid - 4096) * 256 + threadIdx.x;        // 3*16*64*1024
    int k = o & 1023, h = (o >> 10) & 63, n = (o >> 16) & 15, w = o >> 20;
    const float* W = (w == 0) ? wq : (w == 1) ? wk : wv;
    Wt[o] = f2bf(W[(n * 1024 + k) * 64 + h]);
  } else {                                           // Wot (plain transpose)
    int o = (bid - 16384) * 256 + threadIdx.x;       // 1024*1024
    int k = o & 1023, d = o >> 10;
    Wot[o] = f2bf(wo[k * 1024 + d]);
  }
}

// ---------------- GEMM: C[M,c] = A[M,K] * Bt[c,K]^T ----------------
template <int MODE>
__launch_bounds__(256, 2)
__global__ void k_gemm(const unsigned short* __restrict__ A,
                       const unsigned short* __restrict__ Bt,
                       const float* __restrict__ bq, const float* __restrict__ bk,
                       const float* __restrict__ bv, const float* __restrict__ bo,
                       unsigned short* __restrict__ oq, unsigned short* __restrict__ ok_,
                       unsigned short* __restrict__ ov, float* __restrict__ of) {
  __shared__ __align__(16) unsigned short As[128 * 64];
  __shared__ __align__(16) unsigned short Bs[128 * 64];
  const int t = threadIdx.x;
  const int lane = t & 63, wid = t >> 6;
  const int wm = wid >> 1, wn = wid & 1;
  const int l15 = lane & 15, l4 = lane >> 4;
  const int m0 = blockIdx.y * 128, c0 = blockIdx.x * 128;

  f32x4 acc[4][4] = {};

  for (int k0 = 0; k0 < 1024; k0 += 64) {
    if (k0) __syncthreads();
    {
      const int r_l = lane >> 3, kb = lane & 7;
#pragma unroll
      for (int i = 0; i < 4; ++i) {
        int r = wid * 32 + i * 8 + r_l;
        int ksrc = (kb ^ (r & 7)) * 8;               // pre-swizzled global source
        __builtin_amdgcn_global_load_lds(
            (ga_u32*)(A + (long)(m0 + r) * 1024 + k0 + ksrc),
            (lds_u32*)((lds_u16*)As + (wid * 32 + i * 8) * 64), 16, 0, 0);
        __builtin_amdgcn_global_load_lds(
            (ga_u32*)(Bt + (long)(c0 + r) * 1024 + k0 + ksrc),
            (lds_u32*)((lds_u16*)Bs + (wid * 32 + i * 8) * 64), 16, 0, 0);
      }
    }
    __syncthreads();
    s16x8 af[4][2], bf[4][2];
#pragma unroll
    for (int mb = 0; mb < 4; ++mb) {
      int r = wm * 64 + mb * 16 + l15;
#pragma unroll
      for (int kc = 0; kc < 2; ++kc) {
        int byo = (kc * 64 + l4 * 16) ^ ((r & 7) << 4);
        af[mb][kc] = *reinterpret_cast<const s16x8*>(&As[r * 64 + (byo >> 1)]);
      }
    }
#pragma unroll
    for (int nb = 0; nb < 4; ++nb) {
      int r = wn * 64 + nb * 16 + l15;
#pragma unroll
      for (int kc = 0; kc < 2; ++kc) {
        int byo = (kc * 64 + l4 * 16) ^ ((r & 7) << 4);
        bf[nb][kc] = *reinterpret_cast<const s16x8*>(&Bs[r * 64 + (byo >> 1)]);
      }
    }
#pragma unroll
    for (int mb = 0; mb < 4; ++mb)
#pragma unroll
      for (int nb = 0; nb < 4; ++nb) {
        acc[mb][nb] = __builtin_amdgcn_mfma_f32_16x16x32_bf16(af[mb][0], bf[nb][0], acc[mb][nb], 0, 0, 0);
        acc[mb][nb] = __builtin_amdgcn_mfma_f32_16x16x32_bf16(af[mb][1], bf[nb][1], acc[mb][nb], 0, 0, 0);
      }
  }

#pragma unroll
  for (int mb = 0; mb < 4; ++mb) {
#pragma unroll
    for (int nb = 0; nb < 4; ++nb) {
      int c = c0 + wn * 64 + nb * 16 + l15;
      int mbase = m0 + wm * 64 + mb * 16 + l4 * 4;
      if (MODE == 0) {
        int w = c >> 10, cc = c & 1023;
        int nH = cc >> 6, h = cc & 63;
        const float* bias = (w == 0) ? bq : (w == 1) ? bk : bv;
        float bval = bias[cc];
        if (w == 2) {                       // V -> transposed [b][n][h][p]
          int bb = mbase >> 11, p = mbase & 2047;
          u16x4 pk4;
#pragma unroll
          for (int r = 0; r < 4; ++r) pk4[r] = f2bf(acc[mb][nb][r] + bval);
          *reinterpret_cast<u16x4*>(ov + (((long)bb * 16 + nH) * 64 + h) * 2048 + p) = pk4;
        } else {
          unsigned short* dst = (w == 0) ? oq : ok_;
          float scl = (w == 0) ? QSCALE : 1.0f;
#pragma unroll
          for (int r = 0; r < 4; ++r) {
            int m = mbase + r;
            int bb = m >> 11, p = m & 2047;
            dst[(((long)bb * 16 + nH) * 2048 + p) * 64 + h] = f2bf((acc[mb][nb][r] + bval) * scl);
          }
        }
      } else {
#pragma unroll
        for (int r = 0; r < 4; ++r) of[(long)(mbase + r) * 1024 + c] = acc[mb][nb][r] + bo[c];
      }
    }
  }
}

// ---------------- flash attention: mirror-balanced, glds double-buffered ----------------
// 512 blocks x 2 waves; block does q-tiles (qp, 31-qp) of 64 rows: 33 k-tiles always.
__launch_bounds__(128, 1)
__global__ void k_attn(const unsigned short* __restrict__ Q,
                       const unsigned short* __restrict__ K,
                       const unsigned short* __restrict__ VT,
                       unsigned short* __restrict__ Z) {
  __shared__ __align__(16) unsigned short KV[2][2][64 * 64];  // [buf][K/V][64][64] swizzled
  __shared__ unsigned Zl[2][32 * 33];
  const int t = threadIdx.x;
  const int lane = t & 63, wv = t >> 6;
  const int l31 = lane & 31, h5 = lane >> 5;
  const int rl = lane >> 3, cl = lane & 7;
  const int id = blockIdx.x;                    // 512
  const int bn = (id & 7) + 8 * (id >> 7);      // same-bn blocks share an XCD
  const int qp = (id >> 3) & 15;
  const int b = bn >> 4, n = bn & 15;
  const int qtA = qp, qtB = 31 - qp;
  const int nktA = qtA + 1;                     // nktA + nktB == 33 always
  const unsigned short* Qb = Q + (long)bn * (2048 * 64);
  const unsigned short* Kb = K + (long)bn * (2048 * 64);
  const unsigned short* Vb = VT + (long)bn * (64 * 2048);
  unsigned* Zd = (unsigned*)Z;
  const int swl = (l31 & 7) << 4;

  auto stage = [&](int k0s, int nb) {           // wave stages its 32 rows of K and V
#pragma unroll
    for (int i = 0; i < 4; ++i) {
      int r = wv * 32 + i * 8 + rl;
      int cs = (cl ^ (r & 7)) * 8;              // pre-swizzled global source col
      __builtin_amdgcn_global_load_lds(
          (ga_u32*)(Kb + (long)(k0s + r) * 64 + cs),
          (lds_u32*)((lds_u16*)&KV[0][0][0] + ((nb * 2) * 64 + wv * 32 + i * 8) * 64), 16, 0, 0);
      __builtin_amdgcn_global_load_lds(
          (ga_u32*)(Vb + (long)r * 2048 + k0s + cs),
          (lds_u32*)((lds_u16*)&KV[0][0][0] + ((nb * 2 + 1) * 64 + wv * 32 + i * 8) * 64), 16, 0, 0);
    }
  };

  int r0w = qtA * 64 + wv * 32;
  int qq = r0w + l31, qmax = r0w + 31;

  s16x8 qf[4];
#pragma unroll
  for (int hc = 0; hc < 4; ++hc)
    qf[hc] = *reinterpret_cast<const s16x8*>(Qb + (long)qq * 64 + hc * 16 + h5 * 8);

  f32x16 o0 = {}, o1 = {};
  float mrun = -1e30f, lrun = 0.f;

  auto flush = [&](int r0_) {                   // normalize + transpose via Zl + store
    float inv = 1.0f / lrun;
#pragma unroll
    for (int hb = 0; hb < 2; ++hb) {
#pragma unroll
      for (int rp = 0; rp < 8; ++rp) {
        float vlo = (hb ? o1[2 * rp] : o0[2 * rp]) * inv;
        float vhi = (hb ? o1[2 * rp + 1] : o0[2 * rp + 1]) * inv;
        unsigned d = cvtpk(vlo, vhi);
        int col = 16 * hb + 4 * (rp >> 1) + 2 * h5 + (rp & 1);
        Zl[wv][l31 * 33 + col] = d;
      }
    }
    asm volatile("s_waitcnt lgkmcnt(0)" ::: "memory");
    const int qr = lane >> 1, cbs = (lane & 1) * 16;
    const long zb = ((long)(b * 2048 + r0_ + qr)) * 512 + n * 32;
#pragma unroll
    for (int c2 = 0; c2 < 4; ++c2) {
      u32x4 w4;
#pragma unroll
      for (int i2 = 0; i2 < 4; ++i2) w4[i2] = Zl[wv][qr * 33 + cbs + 4 * c2 + i2];
      *reinterpret_cast<u32x4*>(Zd + zb + cbs + 4 * c2) = w4;
    }
  };

  stage(0, 0);                                  // prologue: tile 0 -> buf 0

  for (int idx = 0; idx < 33; ++idx) {
    const int kt = (idx < nktA) ? idx : idx - nktA;
    const int k0 = kt << 6;
    const int cb = idx & 1;
    __syncthreads();                            // drains this tile's glds; frees other buf
    if (idx + 1 < 33) {
      int ktn = (idx + 1 < nktA) ? idx + 1 : idx + 1 - nktA;
      stage(ktn << 6, cb ^ 1);                  // next tile in flight under compute
    }
    if (idx == nktA) {                          // phase switch A -> B
      flush(qtA * 64 + wv * 32);
      r0w = qtB * 64 + wv * 32; qq = r0w + l31; qmax = r0w + 31;
#pragma unroll
      for (int hc = 0; hc < 4; ++hc)
        qf[hc] = *reinterpret_cast<const s16x8*>(Qb + (long)qq * 64 + hc * 16 + h5 * 8);
      o0 = f32x16{}; o1 = f32x16{};
      mrun = -1e30f; lrun = 0.f;
    }
    const unsigned short* Ks = &KV[cb][0][0];
    const unsigned short* Vs = &KV[cb][1][0];
    const bool haveS1 = (k0 + 32 <= qmax);

    // S^T = K . Q^T
    f32x16 s0v = {}, s1v = {};
#pragma unroll
    for (int hc = 0; hc < 4; ++hc) {
      int cbk = hc * 32 + h5 * 16;
      s16x8 kf0 = *reinterpret_cast<const s16x8*>(&Ks[l31 * 64 + ((cbk ^ swl) >> 1)]);
      s0v = __builtin_amdgcn_mfma_f32_32x32x16_bf16(kf0, qf[hc], s0v, 0, 0, 0);
    }
    if (haveS1)
#pragma unroll
      for (int hc = 0; hc < 4; ++hc) {
        int cbk = hc * 32 + h5 * 16;
        s16x8 kf1 = *reinterpret_cast<const s16x8*>(&Ks[(32 + l31) * 64 + ((cbk ^ swl) >> 1)]);
        s1v = __builtin_amdgcn_mfma_f32_32x32x16_bf16(kf1, qf[hc], s1v, 0, 0, 0);
      }

    if (k0 + 63 >= r0w) {                       // diagonal region: mask k > q
#pragma unroll
      for (int r = 0; r < 16; ++r) {
        int kA = k0 + (r & 3) + 8 * (r >> 2) + 4 * h5;
        if (kA > qq) s0v[r] = -1e30f;
        if (kA + 32 > qq) s1v[r] = -1e30f;
      }
    }

    float pmax = s0v[0];
#pragma unroll
    for (int r = 1; r < 16; ++r) pmax = fmaxf(pmax, s0v[r]);
    if (haveS1)
#pragma unroll
      for (int r = 0; r < 16; ++r) pmax = fmaxf(pmax, s1v[r]);
    pmax = fmaxf(pmax, __shfl_xor(pmax, 32));

    if (__any(pmax > mrun + 11.5f)) {           // defer-max (T13, log2 units)
      float mnew = fmaxf(mrun, pmax);
      float scl = __builtin_exp2f(mrun - mnew);
      lrun *= scl;
#pragma unroll
      for (int r = 0; r < 16; ++r) { o0[r] *= scl; o1[r] *= scl; }
      mrun = mnew;
    }
    float rs = 0.f;
#pragma unroll
    for (int r = 0; r < 16; ++r) { s0v[r] = __builtin_exp2f(s0v[r] - mrun); rs += s0v[r]; }
    if (haveS1)
#pragma unroll
      for (int r = 0; r < 16; ++r) { s1v[r] = __builtin_exp2f(s1v[r] - mrun); rs += s1v[r]; }
    rs += __shfl_xor(rs, 32);
    lrun += rs;

    // P -> bf16 B-frags via cvt_pk + permlane32_swap (T12)
    unsigned PK0[8], PK1[8];
#pragma unroll
    for (int m2 = 0; m2 < 8; ++m2) PK0[m2] = cvtpk(s0v[2 * m2], s0v[2 * m2 + 1]);
    if (haveS1)
#pragma unroll
      for (int m2 = 0; m2 < 8; ++m2) PK1[m2] = cvtpk(s1v[2 * m2], s1v[2 * m2 + 1]);

#pragma unroll
    for (int c = 0; c < 4; ++c) {
      if (c >= 2 && !haveS1) break;             // uniform: skip zero k-half
      int base = (c & 1) * 4;
      unsigned x0 = (c >> 1) ? PK1[base + 0] : PK0[base + 0];
      unsigned y0 = (c >> 1) ? PK1[base + 2] : PK0[base + 2];
      unsigned x1 = (c >> 1) ? PK1[base + 1] : PK0[base + 1];
      unsigned y1 = (c >> 1) ? PK1[base + 3] : PK0[base + 3];
      pswap(x0, y0);
      pswap(x1, y1);
      union { s32x4 i; s16x8 h; } u;
      u.i = s32x4{(int)x0, (int)x1, (int)y0, (int)y1};
      int cbv = c * 32 + h5 * 16;
      s16x8 vf0 = *reinterpret_cast<const s16x8*>(&Vs[l31 * 64 + ((cbv ^ swl) >> 1)]);
      s16x8 vf1 = *reinterpret_cast<const s16x8*>(&Vs[(32 + l31) * 64 + ((cbv ^ swl) >> 1)]);
      o0 = __builtin_amdgcn_mfma_f32_32x32x16_bf16(vf0, u.h, o0, 0, 0, 0);
      o1 = __builtin_amdgcn_mfma_f32_32x32x16_bf16(vf1, u.h, o1, 0, 0, 0);
    }
  }

  flush(qtB * 64 + wv * 32);
}

// ---------------- launcher ----------------
extern "C" void kernel_launch(void* const* d_in, const int* in_sizes, int n_in,
                              void* d_out, int out_size, void* d_ws, size_t ws_size,
                              hipStream_t stream) {
  const float* x  = (const float*)d_in[0];
  const float* wq = (const float*)d_in[1];
  const float* wk = (const float*)d_in[2];
  const float* wv = (const float*)d_in[3];
  const float* wo = (const float*)d_in[4];
  const float* bq = (const float*)d_in[5];
  const float* bk = (const float*)d_in[6];
  const float* bv = (const float*)d_in[7];
  const float* bo = (const float*)d_in[8];
  char* ws = (char*)d_ws;
  unsigned short* xb  = (unsigned short*)(ws);                  // 8 MiB  [4096][1024]
  unsigned short* Wt  = (unsigned short*)(ws + (8  << 20));     // 6 MiB  [3][16][64][1024]
  unsigned short* Wot = (unsigned short*)(ws + (14 << 20));     // 2 MiB  [1024][1024]
  unsigned short* Qw  = (unsigned short*)(ws + (16 << 20));     // 8 MiB  [2][16][2048][64]
  unsigned short* Kw  = (unsigned short*)(ws + (24 << 20));     // 8 MiB  [2][16][2048][64]
  unsigned short* Vw  = (unsigned short*)(ws + (32 << 20));     // 8 MiB  [2][16][64][2048] (V^T)
  unsigned short* Zw  = (unsigned short*)(ws + (40 << 20));     // 8 MiB  [4096][1024]
  float* out = (float*)d_out;

  k_prep<<<20480, 256, 0, stream>>>(x, wq, wk, wv, wo, xb, Wt, Wot);
  k_gemm<0><<<dim3(24, 32), 256, 0, stream>>>(xb, Wt, bq, bk, bv, nullptr, Qw, Kw, Vw, nullptr);
  k_attn   <<<512, 128, 0, stream>>>(Qw, Kw, Vw, Zw);
  k_gemm<1><<<dim3(8, 32),  256, 0, stream>>>(Zw, Wot, nullptr, nullptr, nullptr, bo,
                                              nullptr, nullptr, nullptr, out);
}

// Round 6
// 156.594 us; speedup vs baseline: 1.0027x; 1.0027x over previous
//
#include <hip/hip_runtime.h>
#include <hip/hip_bf16.h>

#define DI __device__ __forceinline__

using f32x4  = __attribute__((ext_vector_type(4)))  float;
using f32x16 = __attribute__((ext_vector_type(16))) float;
using s16x8  = __attribute__((ext_vector_type(8)))  short;
using s32x4  = __attribute__((ext_vector_type(4)))  int;
using u16x4  = __attribute__((ext_vector_type(4)))  unsigned short;
using u32x4  = __attribute__((ext_vector_type(4)))  unsigned;

typedef __attribute__((address_space(3))) unsigned       lds_u32;
typedef __attribute__((address_space(3))) unsigned short lds_u16;
typedef const __attribute__((address_space(1))) unsigned ga_u32;

DI unsigned short f2bf(float f) {
  union { float f; unsigned u; } v; v.f = f;
  unsigned r = v.u + 0x7FFFu + ((v.u >> 16) & 1u);   // RNE
  return (unsigned short)(r >> 16);
}

DI unsigned cvtpk(float lo, float hi) {
  unsigned d;
  asm("v_cvt_pk_bf16_f32 %0, %1, %2" : "=v"(d) : "v"(lo), "v"(hi));
  return d;
}
DI void pswap(unsigned &a, unsigned &b) {
  asm("v_permlane32_swap_b32 %0, %1" : "+v"(a), "+v"(b));
}

// Q scale: 1/sqrt(64) * log2(e)  (scores in log2 domain -> exp2 in attn)
#define QSCALE 0.18033688011112042f

// ---------------- fused prep ----------------
__global__ void k_prep(const float* __restrict__ x, const float* __restrict__ wq,
                       const float* __restrict__ wk, const float* __restrict__ wv,
                       const float* __restrict__ wo, unsigned short* __restrict__ xb,
                       unsigned short* __restrict__ Wt, unsigned short* __restrict__ Wot) {
  int bid = blockIdx.x;
  if (bid < 4096) {                                  // x convert, vec4
    int i = (bid * 256 + threadIdx.x) * 4;
    f32x4 v = *reinterpret_cast<const f32x4*>(x + i);
    u16x4 o;
    o[0] = f2bf(v[0]); o[1] = f2bf(v[1]); o[2] = f2bf(v[2]); o[3] = f2bf(v[3]);
    *reinterpret_cast<u16x4*>(xb + i) = o;
  } else if (bid < 16384) {                          // Wt (transpose h<->k)
    int o = (bid - 4096) * 256 + threadIdx.x;        // 3*16*64*1024
    int k = o & 1023, h = (o >> 10) & 63, n = (o >> 16) & 15, w = o >> 20;
    const float* W = (w == 0) ? wq : (w == 1) ? wk : wv;
    Wt[o] = f2bf(W[(n * 1024 + k) * 64 + h]);
  } else {                                           // Wot (plain transpose)
    int o = (bid - 16384) * 256 + threadIdx.x;       // 1024*1024
    int k = o & 1023, d = o >> 10;
    Wot[o] = f2bf(wo[k * 1024 + d]);
  }
}

// ---------------- GEMM: C[M,c] = A[M,K] * Bt[c,K]^T ----------------
template <int MODE>
__launch_bounds__(256, 2)
__global__ void k_gemm(const unsigned short* __restrict__ A,
                       const unsigned short* __restrict__ Bt,
                       const float* __restrict__ bq, const float* __restrict__ bk,
                       const float* __restrict__ bv, const float* __restrict__ bo,
                       unsigned short* __restrict__ oq, unsigned short* __restrict__ ok_,
                       unsigned short* __restrict__ ov, float* __restrict__ of) {
  __shared__ __align__(16) unsigned short As[128 * 64];
  __shared__ __align__(16) unsigned short Bs[128 * 64];
  const int t = threadIdx.x;
  const int lane = t & 63, wid = t >> 6;
  const int wm = wid >> 1, wn = wid & 1;
  const int l15 = lane & 15, l4 = lane >> 4;
  const int m0 = blockIdx.y * 128, c0 = blockIdx.x * 128;

  f32x4 acc[4][4] = {};

  for (int k0 = 0; k0 < 1024; k0 += 64) {
    if (k0) __syncthreads();
    {
      const int r_l = lane >> 3, kb = lane & 7;
#pragma unroll
      for (int i = 0; i < 4; ++i) {
        int r = wid * 32 + i * 8 + r_l;
        int ksrc = (kb ^ (r & 7)) * 8;               // pre-swizzled global source
        __builtin_amdgcn_global_load_lds(
            (ga_u32*)(A + (long)(m0 + r) * 1024 + k0 + ksrc),
            (lds_u32*)((lds_u16*)As + (wid * 32 + i * 8) * 64), 16, 0, 0);
        __builtin_amdgcn_global_load_lds(
            (ga_u32*)(Bt + (long)(c0 + r) * 1024 + k0 + ksrc),
            (lds_u32*)((lds_u16*)Bs + (wid * 32 + i * 8) * 64), 16, 0, 0);
      }
    }
    __syncthreads();
    s16x8 af[4][2], bf[4][2];
#pragma unroll
    for (int mb = 0; mb < 4; ++mb) {
      int r = wm * 64 + mb * 16 + l15;
#pragma unroll
      for (int kc = 0; kc < 2; ++kc) {
        int byo = (kc * 64 + l4 * 16) ^ ((r & 7) << 4);
        af[mb][kc] = *reinterpret_cast<const s16x8*>(&As[r * 64 + (byo >> 1)]);
      }
    }
#pragma unroll
    for (int nb = 0; nb < 4; ++nb) {
      int r = wn * 64 + nb * 16 + l15;
#pragma unroll
      for (int kc = 0; kc < 2; ++kc) {
        int byo = (kc * 64 + l4 * 16) ^ ((r & 7) << 4);
        bf[nb][kc] = *reinterpret_cast<const s16x8*>(&Bs[r * 64 + (byo >> 1)]);
      }
    }
#pragma unroll
    for (int mb = 0; mb < 4; ++mb)
#pragma unroll
      for (int nb = 0; nb < 4; ++nb) {
        acc[mb][nb] = __builtin_amdgcn_mfma_f32_16x16x32_bf16(af[mb][0], bf[nb][0], acc[mb][nb], 0, 0, 0);
        acc[mb][nb] = __builtin_amdgcn_mfma_f32_16x16x32_bf16(af[mb][1], bf[nb][1], acc[mb][nb], 0, 0, 0);
      }
  }

#pragma unroll
  for (int mb = 0; mb < 4; ++mb) {
#pragma unroll
    for (int nb = 0; nb < 4; ++nb) {
      int c = c0 + wn * 64 + nb * 16 + l15;
      int mbase = m0 + wm * 64 + mb * 16 + l4 * 4;
      if (MODE == 0) {
        int w = c >> 10, cc = c & 1023;
        int nH = cc >> 6, h = cc & 63;
        const float* bias = (w == 0) ? bq : (w == 1) ? bk : bv;
        float bval = bias[cc];
        if (w == 2) {                       // V -> transposed [b][n][h][p]
          int bb = mbase >> 11, p = mbase & 2047;
          u16x4 pk4;
#pragma unroll
          for (int r = 0; r < 4; ++r) pk4[r] = f2bf(acc[mb][nb][r] + bval);
          *reinterpret_cast<u16x4*>(ov + (((long)bb * 16 + nH) * 64 + h) * 2048 + p) = pk4;
        } else {
          unsigned short* dst = (w == 0) ? oq : ok_;
          float scl = (w == 0) ? QSCALE : 1.0f;
#pragma unroll
          for (int r = 0; r < 4; ++r) {
            int m = mbase + r;
            int bb = m >> 11, p = m & 2047;
            dst[(((long)bb * 16 + nH) * 2048 + p) * 64 + h] = f2bf((acc[mb][nb][r] + bval) * scl);
          }
        }
      } else {
#pragma unroll
        for (int r = 0; r < 4; ++r) of[(long)(mbase + r) * 1024 + c] = acc[mb][nb][r] + bo[c];
      }
    }
  }
}

// ---------------- flash attention: mirror-balanced, glds double-buffered ----------------
// 512 blocks x 2 waves; block does q-tiles (qp, 31-qp) of 64 rows: 33 k-tiles always.
__launch_bounds__(128, 1)
__global__ void k_attn(const unsigned short* __restrict__ Q,
                       const unsigned short* __restrict__ K,
                       const unsigned short* __restrict__ VT,
                       unsigned short* __restrict__ Z) {
  __shared__ __align__(16) unsigned short KV[2][2][64 * 64];  // [buf][K/V][64][64] swizzled
  __shared__ unsigned Zl[2][32 * 33];
  const int t = threadIdx.x;
  const int lane = t & 63, wv = t >> 6;
  const int l31 = lane & 31, h5 = lane >> 5;
  const int rl = lane >> 3, cl = lane & 7;
  const int id = blockIdx.x;                    // 512
  const int bn = (id & 7) + 8 * (id >> 7);      // same-bn blocks share an XCD
  const int qp = (id >> 3) & 15;
  const int b = bn >> 4, n = bn & 15;
  const int qtA = qp, qtB = 31 - qp;
  const int nktA = qtA + 1;                     // nktA + nktB == 33 always
  const unsigned short* Qb = Q + (long)bn * (2048 * 64);
  const unsigned short* Kb = K + (long)bn * (2048 * 64);
  const unsigned short* Vb = VT + (long)bn * (64 * 2048);
  unsigned* Zd = (unsigned*)Z;
  const int swl = (l31 & 7) << 4;

  auto stage = [&](int k0s, int nb) {           // wave stages its 32 rows of K and V
#pragma unroll
    for (int i = 0; i < 4; ++i) {
      int r = wv * 32 + i * 8 + rl;
      int cs = (cl ^ (r & 7)) * 8;              // pre-swizzled global source col
      __builtin_amdgcn_global_load_lds(
          (ga_u32*)(Kb + (long)(k0s + r) * 64 + cs),
          (lds_u32*)((lds_u16*)&KV[0][0][0] + ((nb * 2) * 64 + wv * 32 + i * 8) * 64), 16, 0, 0);
      __builtin_amdgcn_global_load_lds(
          (ga_u32*)(Vb + (long)r * 2048 + k0s + cs),
          (lds_u32*)((lds_u16*)&KV[0][0][0] + ((nb * 2 + 1) * 64 + wv * 32 + i * 8) * 64), 16, 0, 0);
    }
  };

  int r0w = qtA * 64 + wv * 32;
  int qq = r0w + l31, qmax = r0w + 31;

  s16x8 qf[4];
#pragma unroll
  for (int hc = 0; hc < 4; ++hc)
    qf[hc] = *reinterpret_cast<const s16x8*>(Qb + (long)qq * 64 + hc * 16 + h5 * 8);

  f32x16 o0 = {}, o1 = {};
  float mrun = -1e30f, lrun = 0.f;

  auto flush = [&](int r0_) {                   // normalize + transpose via Zl + store
    float inv = 1.0f / lrun;
#pragma unroll
    for (int hb = 0; hb < 2; ++hb) {
#pragma unroll
      for (int rp = 0; rp < 8; ++rp) {
        float vlo = (hb ? o1[2 * rp] : o0[2 * rp]) * inv;
        float vhi = (hb ? o1[2 * rp + 1] : o0[2 * rp + 1]) * inv;
        unsigned d = cvtpk(vlo, vhi);
        int col = 16 * hb + 4 * (rp >> 1) + 2 * h5 + (rp & 1);
        Zl[wv][l31 * 33 + col] = d;
      }
    }
    asm volatile("s_waitcnt lgkmcnt(0)" ::: "memory");
    const int qr = lane >> 1, cbs = (lane & 1) * 16;
    const long zb = ((long)(b * 2048 + r0_ + qr)) * 512 + n * 32;
#pragma unroll
    for (int c2 = 0; c2 < 4; ++c2) {
      u32x4 w4;
#pragma unroll
      for (int i2 = 0; i2 < 4; ++i2) w4[i2] = Zl[wv][qr * 33 + cbs + 4 * c2 + i2];
      *reinterpret_cast<u32x4*>(Zd + zb + cbs + 4 * c2) = w4;
    }
  };

  stage(0, 0);                                  // prologue: tile 0 -> buf 0

  for (int idx = 0; idx < 33; ++idx) {
    const int kt = (idx < nktA) ? idx : idx - nktA;
    const int k0 = kt << 6;
    const int cb = idx & 1;
    __syncthreads();                            // drains this tile's glds; frees other buf
    if (idx + 1 < 33) {
      int ktn = (idx + 1 < nktA) ? idx + 1 : idx + 1 - nktA;
      stage(ktn << 6, cb ^ 1);                  // next tile in flight under compute
    }
    if (idx == nktA) {                          // phase switch A -> B
      flush(qtA * 64 + wv * 32);
      r0w = qtB * 64 + wv * 32; qq = r0w + l31; qmax = r0w + 31;
#pragma unroll
      for (int hc = 0; hc < 4; ++hc)
        qf[hc] = *reinterpret_cast<const s16x8*>(Qb + (long)qq * 64 + hc * 16 + h5 * 8);
      o0 = f32x16{}; o1 = f32x16{};
      mrun = -1e30f; lrun = 0.f;
    }
    const unsigned short* Ks = &KV[cb][0][0];
    const unsigned short* Vs = &KV[cb][1][0];
    const bool haveS1 = (k0 + 32 <= qmax);

    // S^T = K . Q^T
    f32x16 s0v = {}, s1v = {};
#pragma unroll
    for (int hc = 0; hc < 4; ++hc) {
      int cbk = hc * 32 + h5 * 16;
      s16x8 kf0 = *reinterpret_cast<const s16x8*>(&Ks[l31 * 64 + ((cbk ^ swl) >> 1)]);
      s0v = __builtin_amdgcn_mfma_f32_32x32x16_bf16(kf0, qf[hc], s0v, 0, 0, 0);
    }
    if (haveS1)
#pragma unroll
      for (int hc = 0; hc < 4; ++hc) {
        int cbk = hc * 32 + h5 * 16;
        s16x8 kf1 = *reinterpret_cast<const s16x8*>(&Ks[(32 + l31) * 64 + ((cbk ^ swl) >> 1)]);
        s1v = __builtin_amdgcn_mfma_f32_32x32x16_bf16(kf1, qf[hc], s1v, 0, 0, 0);
      }

    if (k0 + 63 >= r0w) {                       // diagonal region: mask k > q
#pragma unroll
      for (int r = 0; r < 16; ++r) {
        int kA = k0 + (r & 3) + 8 * (r >> 2) + 4 * h5;
        if (kA > qq) s0v[r] = -1e30f;
        if (kA + 32 > qq) s1v[r] = -1e30f;
      }
    }

    float pmax = s0v[0];
#pragma unroll
    for (int r = 1; r < 16; ++r) pmax = fmaxf(pmax, s0v[r]);
    if (haveS1)
#pragma unroll
      for (int r = 0; r < 16; ++r) pmax = fmaxf(pmax, s1v[r]);
    pmax = fmaxf(pmax, __shfl_xor(pmax, 32));

    if (__any(pmax > mrun + 11.5f)) {           // defer-max (T13, log2 units)
      float mnew = fmaxf(mrun, pmax);
      float scl = __builtin_exp2f(mrun - mnew);
      lrun *= scl;
#pragma unroll
      for (int r = 0; r < 16; ++r) { o0[r] *= scl; o1[r] *= scl; }
      mrun = mnew;
    }
    float rs = 0.f;
#pragma unroll
    for (int r = 0; r < 16; ++r) { s0v[r] = __builtin_exp2f(s0v[r] - mrun); rs += s0v[r]; }
    if (haveS1)
#pragma unroll
      for (int r = 0; r < 16; ++r) { s1v[r] = __builtin_exp2f(s1v[r] - mrun); rs += s1v[r]; }
    rs += __shfl_xor(rs, 32);
    lrun += rs;

    // P -> bf16 B-frags via cvt_pk + permlane32_swap (T12)
    unsigned PK0[8], PK1[8];
#pragma unroll
    for (int m2 = 0; m2 < 8; ++m2) PK0[m2] = cvtpk(s0v[2 * m2], s0v[2 * m2 + 1]);
    if (haveS1)
#pragma unroll
      for (int m2 = 0; m2 < 8; ++m2) PK1[m2] = cvtpk(s1v[2 * m2], s1v[2 * m2 + 1]);

#pragma unroll
    for (int c = 0; c < 4; ++c) {
      if (c >= 2 && !haveS1) break;             // uniform: skip zero k-half
      int base = (c & 1) * 4;
      unsigned x0 = (c >> 1) ? PK1[base + 0] : PK0[base + 0];
      unsigned y0 = (c >> 1) ? PK1[base + 2] : PK0[base + 2];
      unsigned x1 = (c >> 1) ? PK1[base + 1] : PK0[base + 1];
      unsigned y1 = (c >> 1) ? PK1[base + 3] : PK0[base + 3];
      pswap(x0, y0);
      pswap(x1, y1);
      union { s32x4 i; s16x8 h; } u;
      u.i = s32x4{(int)x0, (int)x1, (int)y0, (int)y1};
      int cbv = c * 32 + h5 * 16;
      s16x8 vf0 = *reinterpret_cast<const s16x8*>(&Vs[l31 * 64 + ((cbv ^ swl) >> 1)]);
      s16x8 vf1 = *reinterpret_cast<const s16x8*>(&Vs[(32 + l31) * 64 + ((cbv ^ swl) >> 1)]);
      o0 = __builtin_amdgcn_mfma_f32_32x32x16_bf16(vf0, u.h, o0, 0, 0, 0);
      o1 = __builtin_amdgcn_mfma_f32_32x32x16_bf16(vf1, u.h, o1, 0, 0, 0);
    }
  }

  flush(qtB * 64 + wv * 32);
}

// ---------------- launcher ----------------
extern "C" void kernel_launch(void* const* d_in, const int* in_sizes, int n_in,
                              void* d_out, int out_size, void* d_ws, size_t ws_size,
                              hipStream_t stream) {
  const float* x  = (const float*)d_in[0];
  const float* wq = (const float*)d_in[1];
  const float* wk = (const float*)d_in[2];
  const float* wv = (const float*)d_in[3];
  const float* wo = (const float*)d_in[4];
  const float* bq = (const float*)d_in[5];
  const float* bk = (const float*)d_in[6];
  const float* bv = (const float*)d_in[7];
  const float* bo = (const float*)d_in[8];
  char* ws = (char*)d_ws;
  unsigned short* xb  = (unsigned short*)(ws);                  // 8 MiB  [4096][1024]
  unsigned short* Wt  = (unsigned short*)(ws + (8  << 20));     // 6 MiB  [3][16][64][1024]
  unsigned short* Wot = (unsigned short*)(ws + (14 << 20));     // 2 MiB  [1024][1024]
  unsigned short* Qw  = (unsigned short*)(ws + (16 << 20));     // 8 MiB  [2][16][2048][64]
  unsigned short* Kw  = (unsigned short*)(ws + (24 << 20));     // 8 MiB  [2][16][2048][64]
  unsigned short* Vw  = (unsigned short*)(ws + (32 << 20));     // 8 MiB  [2][16][64][2048] (V^T)
  unsigned short* Zw  = (unsigned short*)(ws + (40 << 20));     // 8 MiB  [4096][1024]
  float* out = (float*)d_out;

  k_prep<<<20480, 256, 0, stream>>>(x, wq, wk, wv, wo, xb, Wt, Wot);
  k_gemm<0><<<dim3(24, 32), 256, 0, stream>>>(xb, Wt, bq, bk, bv, nullptr, Qw, Kw, Vw, nullptr);
  k_attn   <<<512, 128, 0, stream>>>(Qw, Kw, Vw, Zw);
  k_gemm<1><<<dim3(8, 32),  256, 0, stream>>>(Zw, Wot, nullptr, nullptr, nullptr, bo,
                                              nullptr, nullptr, nullptr, out);
}

// Round 7
// 131.598 us; speedup vs baseline: 1.1932x; 1.1899x over previous
//
#include <hip/hip_runtime.h>
#include <hip/hip_bf16.h>

#define DI __device__ __forceinline__

using f32x4  = __attribute__((ext_vector_type(4)))  float;
using f32x16 = __attribute__((ext_vector_type(16))) float;
using s16x8  = __attribute__((ext_vector_type(8)))  short;
using s32x4  = __attribute__((ext_vector_type(4)))  int;
using u16x4  = __attribute__((ext_vector_type(4)))  unsigned short;
using u32x4  = __attribute__((ext_vector_type(4)))  unsigned;

typedef __attribute__((address_space(3))) unsigned       lds_u32;
typedef __attribute__((address_space(3))) unsigned short lds_u16;
typedef const __attribute__((address_space(1))) unsigned ga_u32;

DI unsigned short f2bf(float f) {
  union { float f; unsigned u; } v; v.f = f;
  unsigned r = v.u + 0x7FFFu + ((v.u >> 16) & 1u);   // RNE
  return (unsigned short)(r >> 16);
}

DI unsigned cvtpk(float lo, float hi) {
  unsigned d;
  asm("v_cvt_pk_bf16_f32 %0, %1, %2" : "=v"(d) : "v"(lo), "v"(hi));
  return d;
}
DI void pswap(unsigned &a, unsigned &b) {
  asm("v_permlane32_swap_b32 %0, %1" : "+v"(a), "+v"(b));
}

// Q scale: 1/sqrt(64) * log2(e)  (scores in log2 domain -> exp2 in attn)
#define QSCALE 0.18033688011112042f

// ---------------- fused prep ----------------
__global__ void k_prep(const float* __restrict__ x, const float* __restrict__ wq,
                       const float* __restrict__ wk, const float* __restrict__ wv,
                       const float* __restrict__ wo, unsigned short* __restrict__ xb,
                       unsigned short* __restrict__ Wt, unsigned short* __restrict__ Wot) {
  int bid = blockIdx.x;
  if (bid < 4096) {                                  // x convert, vec4
    int i = (bid * 256 + threadIdx.x) * 4;
    f32x4 v = *reinterpret_cast<const f32x4*>(x + i);
    u16x4 o;
    o[0] = f2bf(v[0]); o[1] = f2bf(v[1]); o[2] = f2bf(v[2]); o[3] = f2bf(v[3]);
    *reinterpret_cast<u16x4*>(xb + i) = o;
  } else if (bid < 16384) {                          // Wt (transpose h<->k)
    int o = (bid - 4096) * 256 + threadIdx.x;        // 3*16*64*1024
    int k = o & 1023, h = (o >> 10) & 63, n = (o >> 16) & 15, w = o >> 20;
    const float* W = (w == 0) ? wq : (w == 1) ? wk : wv;
    Wt[o] = f2bf(W[(n * 1024 + k) * 64 + h]);
  } else {                                           // Wot (plain transpose)
    int o = (bid - 16384) * 256 + threadIdx.x;       // 1024*1024
    int k = o & 1023, d = o >> 10;
    Wot[o] = f2bf(wo[k * 1024 + d]);
  }
}

// ---------------- GEMM: C[M,c] = A[M,K] * Bt[c,K]^T ----------------
template <int MODE>
__launch_bounds__(256, 2)
__global__ void k_gemm(const unsigned short* __restrict__ A,
                       const unsigned short* __restrict__ Bt,
                       const float* __restrict__ bq, const float* __restrict__ bk,
                       const float* __restrict__ bv, const float* __restrict__ bo,
                       unsigned short* __restrict__ oq, unsigned short* __restrict__ ok_,
                       unsigned short* __restrict__ ov, float* __restrict__ of) {
  __shared__ __align__(16) unsigned short As[128 * 64];
  __shared__ __align__(16) unsigned short Bs[128 * 64];
  const int t = threadIdx.x;
  const int lane = t & 63, wid = t >> 6;
  const int wm = wid >> 1, wn = wid & 1;
  const int l15 = lane & 15, l4 = lane >> 4;
  const int m0 = blockIdx.y * 128, c0 = blockIdx.x * 128;

  f32x4 acc[4][4] = {};

  for (int k0 = 0; k0 < 1024; k0 += 64) {
    if (k0) __syncthreads();
    {
      const int r_l = lane >> 3, kb = lane & 7;
#pragma unroll
      for (int i = 0; i < 4; ++i) {
        int r = wid * 32 + i * 8 + r_l;
        int ksrc = (kb ^ (r & 7)) * 8;               // pre-swizzled global source
        __builtin_amdgcn_global_load_lds(
            (ga_u32*)(A + (long)(m0 + r) * 1024 + k0 + ksrc),
            (lds_u32*)((lds_u16*)As + (wid * 32 + i * 8) * 64), 16, 0, 0);
        __builtin_amdgcn_global_load_lds(
            (ga_u32*)(Bt + (long)(c0 + r) * 1024 + k0 + ksrc),
            (lds_u32*)((lds_u16*)Bs + (wid * 32 + i * 8) * 64), 16, 0, 0);
      }
    }
    __syncthreads();
    s16x8 af[4][2], bf[4][2];
#pragma unroll
    for (int mb = 0; mb < 4; ++mb) {
      int r = wm * 64 + mb * 16 + l15;
#pragma unroll
      for (int kc = 0; kc < 2; ++kc) {
        int byo = (kc * 64 + l4 * 16) ^ ((r & 7) << 4);
        af[mb][kc] = *reinterpret_cast<const s16x8*>(&As[r * 64 + (byo >> 1)]);
      }
    }
#pragma unroll
    for (int nb = 0; nb < 4; ++nb) {
      int r = wn * 64 + nb * 16 + l15;
#pragma unroll
      for (int kc = 0; kc < 2; ++kc) {
        int byo = (kc * 64 + l4 * 16) ^ ((r & 7) << 4);
        bf[nb][kc] = *reinterpret_cast<const s16x8*>(&Bs[r * 64 + (byo >> 1)]);
      }
    }
#pragma unroll
    for (int mb = 0; mb < 4; ++mb)
#pragma unroll
      for (int nb = 0; nb < 4; ++nb) {
        acc[mb][nb] = __builtin_amdgcn_mfma_f32_16x16x32_bf16(af[mb][0], bf[nb][0], acc[mb][nb], 0, 0, 0);
        acc[mb][nb] = __builtin_amdgcn_mfma_f32_16x16x32_bf16(af[mb][1], bf[nb][1], acc[mb][nb], 0, 0, 0);
      }
  }

#pragma unroll
  for (int mb = 0; mb < 4; ++mb) {
#pragma unroll
    for (int nb = 0; nb < 4; ++nb) {
      int c = c0 + wn * 64 + nb * 16 + l15;
      int mbase = m0 + wm * 64 + mb * 16 + l4 * 4;
      if (MODE == 0) {
        int w = c >> 10, cc = c & 1023;
        int nH = cc >> 6, h = cc & 63;
        const float* bias = (w == 0) ? bq : (w == 1) ? bk : bv;
        float bval = bias[cc];
        if (w == 2) {                       // V -> transposed [b][n][h][p]
          int bb = mbase >> 11, p = mbase & 2047;
          u16x4 pk4;
#pragma unroll
          for (int r = 0; r < 4; ++r) pk4[r] = f2bf(acc[mb][nb][r] + bval);
          *reinterpret_cast<u16x4*>(ov + (((long)bb * 16 + nH) * 64 + h) * 2048 + p) = pk4;
        } else {
          unsigned short* dst = (w == 0) ? oq : ok_;
          float scl = (w == 0) ? QSCALE : 1.0f;
#pragma unroll
          for (int r = 0; r < 4; ++r) {
            int m = mbase + r;
            int bb = m >> 11, p = m & 2047;
            dst[(((long)bb * 16 + nH) * 2048 + p) * 64 + h] = f2bf((acc[mb][nb][r] + bval) * scl);
          }
        }
      } else {
#pragma unroll
        for (int r = 0; r < 4; ++r) of[(long)(mbase + r) * 1024 + c] = acc[mb][nb][r] + bo[c];
      }
    }
  }
}

// ---------------- flash attention: 4 waves/block, 128-row q-tile, LPT order ----------------
// 512 blocks x 256 thr; block = (bn, qt), waves own 32-row groups; nkt = 2qt+2 uniform.
__launch_bounds__(256, 2)
__global__ void k_attn(const unsigned short* __restrict__ Q,
                       const unsigned short* __restrict__ K,
                       const unsigned short* __restrict__ VT,
                       unsigned short* __restrict__ Z) {
  __shared__ __align__(16) unsigned short KV[2][2][64 * 64];  // [buf][K/V][64][64] swizzled
  __shared__ unsigned Zl[4][32 * 33];
  const int t = threadIdx.x;
  const int lane = t & 63, wv = t >> 6;
  const int l31 = lane & 31, h5 = lane >> 5;
  const int rl = lane >> 3, cl = lane & 7;
  const int id = blockIdx.x;                    // 512
  const int xcd = id & 7, j = id >> 3;
  const int bn = (j & 3) * 8 + xcd;             // 4 bn per XCD (K/V fits XCD L2)
  const int qt = 15 - (j >> 2);                 // heavy q-tiles dispatch first (LPT)
  const int b = bn >> 4, n = bn & 15;
  const int r0w = qt * 128 + wv * 32;           // this wave's 32 q-rows
  const int qq = r0w + l31, qmax = r0w + 31;
  const int nkt = 2 * qt + 2;
  const unsigned short* Qb = Q + (long)bn * (2048 * 64);
  const unsigned short* Kb = K + (long)bn * (2048 * 64);
  const unsigned short* Vb = VT + (long)bn * (64 * 2048);
  unsigned* Zd = (unsigned*)Z;
  const int swl = (l31 & 7) << 4;

  auto stage = [&](int k0s, int nb) {           // wave stages 16 rows of K and of V
#pragma unroll
    for (int i = 0; i < 2; ++i) {
      int rbase = wv * 16 + i * 8;
      int r = rbase + rl;
      int cs = (cl ^ (r & 7)) * 8;              // pre-swizzled global source col
      __builtin_amdgcn_global_load_lds(
          (ga_u32*)(Kb + (long)(k0s + r) * 64 + cs),
          (lds_u32*)((lds_u16*)&KV[nb][0][0] + rbase * 64), 16, 0, 0);
      __builtin_amdgcn_global_load_lds(
          (ga_u32*)(Vb + (long)r * 2048 + k0s + cs),
          (lds_u32*)((lds_u16*)&KV[nb][1][0] + rbase * 64), 16, 0, 0);
    }
  };

  s16x8 qf[4];
#pragma unroll
  for (int hc = 0; hc < 4; ++hc)
    qf[hc] = *reinterpret_cast<const s16x8*>(Qb + (long)qq * 64 + hc * 16 + h5 * 8);

  f32x16 o0 = {}, o1 = {};                      // O^T[h][q]
  float mrun = -1e30f, lrun = 0.f;

  stage(0, 0);                                  // prologue: tile 0 -> buf 0

  for (int kt = 0; kt < nkt; ++kt) {
    const int k0 = kt << 6;
    const int cb = kt & 1;
    __syncthreads();                            // drains this tile's glds; frees other buf
    if (kt + 1 < nkt) stage((kt + 1) << 6, cb ^ 1);
    if (k0 > qmax) continue;                    // fully-masked tail tile (waves 0,1)

    const unsigned short* Ks = &KV[cb][0][0];
    const unsigned short* Vs = &KV[cb][1][0];
    const bool haveS1 = (k0 + 32 <= qmax);

    // S^T = K . Q^T
    f32x16 s0v = {}, s1v = {};
    __builtin_amdgcn_s_setprio(1);
#pragma unroll
    for (int hc = 0; hc < 4; ++hc) {
      int cbk = hc * 32 + h5 * 16;
      s16x8 kf0 = *reinterpret_cast<const s16x8*>(&Ks[l31 * 64 + ((cbk ^ swl) >> 1)]);
      s0v = __builtin_amdgcn_mfma_f32_32x32x16_bf16(kf0, qf[hc], s0v, 0, 0, 0);
    }
    if (haveS1)
#pragma unroll
      for (int hc = 0; hc < 4; ++hc) {
        int cbk = hc * 32 + h5 * 16;
        s16x8 kf1 = *reinterpret_cast<const s16x8*>(&Ks[(32 + l31) * 64 + ((cbk ^ swl) >> 1)]);
        s1v = __builtin_amdgcn_mfma_f32_32x32x16_bf16(kf1, qf[hc], s1v, 0, 0, 0);
      }
    __builtin_amdgcn_s_setprio(0);

    if (k0 + 63 > r0w) {                        // diagonal region: mask k > q
#pragma unroll
      for (int r = 0; r < 16; ++r) {
        int kA = k0 + (r & 3) + 8 * (r >> 2) + 4 * h5;
        if (kA > qq) s0v[r] = -1e30f;
        if (kA + 32 > qq) s1v[r] = -1e30f;
      }
    }

    float pmax = s0v[0];
#pragma unroll
    for (int r = 1; r < 16; ++r) pmax = fmaxf(pmax, s0v[r]);
    if (haveS1)
#pragma unroll
      for (int r = 0; r < 16; ++r) pmax = fmaxf(pmax, s1v[r]);
    pmax = fmaxf(pmax, __shfl_xor(pmax, 32));

    if (__any(pmax > mrun + 11.5f)) {           // defer-max (T13, log2 units)
      float mnew = fmaxf(mrun, pmax);
      float scl = __builtin_exp2f(mrun - mnew);
      lrun *= scl;
#pragma unroll
      for (int r = 0; r < 16; ++r) { o0[r] *= scl; o1[r] *= scl; }
      mrun = mnew;
    }
    float rs = 0.f;
#pragma unroll
    for (int r = 0; r < 16; ++r) { s0v[r] = __builtin_exp2f(s0v[r] - mrun); rs += s0v[r]; }
    if (haveS1)
#pragma unroll
      for (int r = 0; r < 16; ++r) { s1v[r] = __builtin_exp2f(s1v[r] - mrun); rs += s1v[r]; }
    rs += __shfl_xor(rs, 32);
    lrun += rs;

    // P -> bf16 B-frags via cvt_pk + permlane32_swap (T12)
    unsigned PK0[8], PK1[8];
#pragma unroll
    for (int m2 = 0; m2 < 8; ++m2) PK0[m2] = cvtpk(s0v[2 * m2], s0v[2 * m2 + 1]);
    if (haveS1)
#pragma unroll
      for (int m2 = 0; m2 < 8; ++m2) PK1[m2] = cvtpk(s1v[2 * m2], s1v[2 * m2 + 1]);

    __builtin_amdgcn_s_setprio(1);
#pragma unroll
    for (int c = 0; c < 4; ++c) {
      if (c >= 2 && !haveS1) break;             // uniform: skip zero k-half
      int base = (c & 1) * 4;
      unsigned x0 = (c >> 1) ? PK1[base + 0] : PK0[base + 0];
      unsigned y0 = (c >> 1) ? PK1[base + 2] : PK0[base + 2];
      unsigned x1 = (c >> 1) ? PK1[base + 1] : PK0[base + 1];
      unsigned y1 = (c >> 1) ? PK1[base + 3] : PK0[base + 3];
      pswap(x0, y0);
      pswap(x1, y1);
      union { s32x4 i; s16x8 h; } u;
      u.i = s32x4{(int)x0, (int)x1, (int)y0, (int)y1};
      int cbv = c * 32 + h5 * 16;
      s16x8 vf0 = *reinterpret_cast<const s16x8*>(&Vs[l31 * 64 + ((cbv ^ swl) >> 1)]);
      s16x8 vf1 = *reinterpret_cast<const s16x8*>(&Vs[(32 + l31) * 64 + ((cbv ^ swl) >> 1)]);
      o0 = __builtin_amdgcn_mfma_f32_32x32x16_bf16(vf0, u.h, o0, 0, 0, 0);
      o1 = __builtin_amdgcn_mfma_f32_32x32x16_bf16(vf1, u.h, o1, 0, 0, 0);
    }
    __builtin_amdgcn_s_setprio(0);
  }

  // epilogue: normalize, transpose O^T->O via wave-private LDS, coalesced store
  float inv = 1.0f / lrun;
#pragma unroll
  for (int hb = 0; hb < 2; ++hb) {
#pragma unroll
    for (int rp = 0; rp < 8; ++rp) {
      float vlo = (hb ? o1[2 * rp] : o0[2 * rp]) * inv;
      float vhi = (hb ? o1[2 * rp + 1] : o0[2 * rp + 1]) * inv;
      unsigned d = cvtpk(vlo, vhi);
      int col = 16 * hb + 4 * (rp >> 1) + 2 * h5 + (rp & 1);
      Zl[wv][l31 * 33 + col] = d;
    }
  }
  asm volatile("s_waitcnt lgkmcnt(0)" ::: "memory");   // wave-local LDS ordering
  const int qr = lane >> 1, cbs = (lane & 1) * 16;
  const long zb = ((long)(b * 2048 + r0w + qr)) * 512 + n * 32;   // dword index
#pragma unroll
  for (int c2 = 0; c2 < 4; ++c2) {
    u32x4 w4;
#pragma unroll
    for (int i2 = 0; i2 < 4; ++i2) w4[i2] = Zl[wv][qr * 33 + cbs + 4 * c2 + i2];
    *reinterpret_cast<u32x4*>(Zd + zb + cbs + 4 * c2) = w4;
  }
}

// ---------------- launcher ----------------
extern "C" void kernel_launch(void* const* d_in, const int* in_sizes, int n_in,
                              void* d_out, int out_size, void* d_ws, size_t ws_size,
                              hipStream_t stream) {
  const float* x  = (const float*)d_in[0];
  const float* wq = (const float*)d_in[1];
  const float* wk = (const float*)d_in[2];
  const float* wv = (const float*)d_in[3];
  const float* wo = (const float*)d_in[4];
  const float* bq = (const float*)d_in[5];
  const float* bk = (const float*)d_in[6];
  const float* bv = (const float*)d_in[7];
  const float* bo = (const float*)d_in[8];
  char* ws = (char*)d_ws;
  unsigned short* xb  = (unsigned short*)(ws);                  // 8 MiB  [4096][1024]
  unsigned short* Wt  = (unsigned short*)(ws + (8  << 20));     // 6 MiB  [3][16][64][1024]
  unsigned short* Wot = (unsigned short*)(ws + (14 << 20));     // 2 MiB  [1024][1024]
  unsigned short* Qw  = (unsigned short*)(ws + (16 << 20));     // 8 MiB  [2][16][2048][64]
  unsigned short* Kw  = (unsigned short*)(ws + (24 << 20));     // 8 MiB  [2][16][2048][64]
  unsigned short* Vw  = (unsigned short*)(ws + (32 << 20));     // 8 MiB  [2][16][64][2048] (V^T)
  unsigned short* Zw  = (unsigned short*)(ws + (40 << 20));     // 8 MiB  [4096][1024]
  float* out = (float*)d_out;

  k_prep<<<20480, 256, 0, stream>>>(x, wq, wk, wv, wo, xb, Wt, Wot);
  k_gemm<0><<<dim3(24, 32), 256, 0, stream>>>(xb, Wt, bq, bk, bv, nullptr, Qw, Kw, Vw, nullptr);
  k_attn   <<<512, 256, 0, stream>>>(Qw, Kw, Vw, Zw);
  k_gemm<1><<<dim3(8, 32),  256, 0, stream>>>(Zw, Wot, nullptr, nullptr, nullptr, bo,
                                              nullptr, nullptr, nullptr, out);
}

// Round 8
// 125.837 us; speedup vs baseline: 1.2478x; 1.0458x over previous
//
#include <hip/hip_runtime.h>
#include <hip/hip_bf16.h>

#define DI __device__ __forceinline__

using f32x4  = __attribute__((ext_vector_type(4)))  float;
using f32x16 = __attribute__((ext_vector_type(16))) float;
using s16x8  = __attribute__((ext_vector_type(8)))  short;
using s32x4  = __attribute__((ext_vector_type(4)))  int;
using u16x4  = __attribute__((ext_vector_type(4)))  unsigned short;
using u32x4  = __attribute__((ext_vector_type(4)))  unsigned;

typedef __attribute__((address_space(3))) unsigned       lds_u32;
typedef __attribute__((address_space(3))) unsigned short lds_u16;
typedef const __attribute__((address_space(1))) unsigned ga_u32;

DI unsigned short f2bf(float f) {
  union { float f; unsigned u; } v; v.f = f;
  unsigned r = v.u + 0x7FFFu + ((v.u >> 16) & 1u);   // RNE
  return (unsigned short)(r >> 16);
}

DI unsigned cvtpk(float lo, float hi) {
  unsigned d;
  asm("v_cvt_pk_bf16_f32 %0, %1, %2" : "=v"(d) : "v"(lo), "v"(hi));
  return d;
}
DI void pswap(unsigned &a, unsigned &b) {
  asm("v_permlane32_swap_b32 %0, %1" : "+v"(a), "+v"(b));
}

// Q scale: 1/sqrt(64) * log2(e)  (scores in log2 domain -> exp2 in attn)
#define QSCALE 0.18033688011112042f

// ---------------- fused prep ----------------
__global__ void k_prep(const float* __restrict__ x, const float* __restrict__ wq,
                       const float* __restrict__ wk, const float* __restrict__ wv,
                       const float* __restrict__ wo, unsigned short* __restrict__ xb,
                       unsigned short* __restrict__ Wt, unsigned short* __restrict__ Wot) {
  int bid = blockIdx.x;
  if (bid < 4096) {                                  // x convert, vec4
    int i = (bid * 256 + threadIdx.x) * 4;
    f32x4 v = *reinterpret_cast<const f32x4*>(x + i);
    u16x4 o;
    o[0] = f2bf(v[0]); o[1] = f2bf(v[1]); o[2] = f2bf(v[2]); o[3] = f2bf(v[3]);
    *reinterpret_cast<u16x4*>(xb + i) = o;
  } else if (bid < 16384) {                          // Wt (transpose h<->k)
    int o = (bid - 4096) * 256 + threadIdx.x;        // 3*16*64*1024
    int k = o & 1023, h = (o >> 10) & 63, n = (o >> 16) & 15, w = o >> 20;
    const float* W = (w == 0) ? wq : (w == 1) ? wk : wv;
    Wt[o] = f2bf(W[(n * 1024 + k) * 64 + h]);
  } else {                                           // Wot (plain transpose)
    int o = (bid - 16384) * 256 + threadIdx.x;       // 1024*1024
    int k = o & 1023, d = o >> 10;
    Wot[o] = f2bf(wo[k * 1024 + d]);
  }
}

// ---------------- GEMM: C[M,c] = A[M,K] * Bt[c,K]^T ----------------
// BM = 128 (MODE 0) or 64 (MODE 1). N-tile fixed 128.
template <int MODE, int BM>
__launch_bounds__(256, 3)
__global__ void k_gemm(const unsigned short* __restrict__ A,
                       const unsigned short* __restrict__ Bt,
                       const float* __restrict__ bq, const float* __restrict__ bk,
                       const float* __restrict__ bv, const float* __restrict__ bo,
                       unsigned short* __restrict__ oq, unsigned short* __restrict__ ok_,
                       unsigned short* __restrict__ ov, float* __restrict__ of) {
  constexpr int MFR = BM / 32;                       // m-frags per wave
  __shared__ __align__(16) unsigned short As[BM * 64];
  __shared__ __align__(16) unsigned short Bs[128 * 64];
  const int t = threadIdx.x;
  const int lane = t & 63, wid = t >> 6;
  const int wm = wid >> 1, wn = wid & 1;
  const int l15 = lane & 15, l4 = lane >> 4;
  const int m0 = blockIdx.y * BM, c0 = blockIdx.x * 128;

  f32x4 acc[MFR][4] = {};

  for (int k0 = 0; k0 < 1024; k0 += 64) {
    if (k0) __syncthreads();
    {
      const int r_l = lane >> 3, kb = lane & 7;
#pragma unroll
      for (int i = 0; i < MFR; ++i) {                // A: BM rows
        int rbase = wid * (BM / 4) + i * 8;
        int r = rbase + r_l;
        int ksrc = (kb ^ (r & 7)) * 8;               // pre-swizzled global source
        __builtin_amdgcn_global_load_lds(
            (ga_u32*)(A + (long)(m0 + r) * 1024 + k0 + ksrc),
            (lds_u32*)((lds_u16*)As + rbase * 64), 16, 0, 0);
      }
#pragma unroll
      for (int i = 0; i < 4; ++i) {                  // B: 128 rows
        int rbase = wid * 32 + i * 8;
        int r = rbase + r_l;
        int ksrc = (kb ^ (r & 7)) * 8;
        __builtin_amdgcn_global_load_lds(
            (ga_u32*)(Bt + (long)(c0 + r) * 1024 + k0 + ksrc),
            (lds_u32*)((lds_u16*)Bs + rbase * 64), 16, 0, 0);
      }
    }
    __syncthreads();
    s16x8 af[MFR][2], bf[4][2];
#pragma unroll
    for (int mb = 0; mb < MFR; ++mb) {
      int r = wm * (BM / 2) + mb * 16 + l15;
#pragma unroll
      for (int kc = 0; kc < 2; ++kc) {
        int byo = (kc * 64 + l4 * 16) ^ ((r & 7) << 4);
        af[mb][kc] = *reinterpret_cast<const s16x8*>(&As[r * 64 + (byo >> 1)]);
      }
    }
#pragma unroll
    for (int nb = 0; nb < 4; ++nb) {
      int r = wn * 64 + nb * 16 + l15;
#pragma unroll
      for (int kc = 0; kc < 2; ++kc) {
        int byo = (kc * 64 + l4 * 16) ^ ((r & 7) << 4);
        bf[nb][kc] = *reinterpret_cast<const s16x8*>(&Bs[r * 64 + (byo >> 1)]);
      }
    }
#pragma unroll
    for (int mb = 0; mb < MFR; ++mb)
#pragma unroll
      for (int nb = 0; nb < 4; ++nb) {
        acc[mb][nb] = __builtin_amdgcn_mfma_f32_16x16x32_bf16(af[mb][0], bf[nb][0], acc[mb][nb], 0, 0, 0);
        acc[mb][nb] = __builtin_amdgcn_mfma_f32_16x16x32_bf16(af[mb][1], bf[nb][1], acc[mb][nb], 0, 0, 0);
      }
  }

#pragma unroll
  for (int mb = 0; mb < MFR; ++mb) {
#pragma unroll
    for (int nb = 0; nb < 4; ++nb) {
      int c = c0 + wn * 64 + nb * 16 + l15;
      int mbase = m0 + wm * (BM / 2) + mb * 16 + l4 * 4;
      if (MODE == 0) {
        int w = c >> 10, cc = c & 1023;
        int nH = cc >> 6, h = cc & 63;
        const float* bias = (w == 0) ? bq : (w == 1) ? bk : bv;
        float bval = bias[cc];
        if (w == 2) {                       // V -> transposed [b][n][h][p]
          int bb = mbase >> 11, p = mbase & 2047;
          u16x4 pk4;
#pragma unroll
          for (int r = 0; r < 4; ++r) pk4[r] = f2bf(acc[mb][nb][r] + bval);
          *reinterpret_cast<u16x4*>(ov + (((long)bb * 16 + nH) * 64 + h) * 2048 + p) = pk4;
        } else {
          unsigned short* dst = (w == 0) ? oq : ok_;
          float scl = (w == 0) ? QSCALE : 1.0f;
#pragma unroll
          for (int r = 0; r < 4; ++r) {
            int m = mbase + r;
            int bb = m >> 11, p = m & 2047;
            dst[(((long)bb * 16 + nH) * 2048 + p) * 64 + h] = f2bf((acc[mb][nb][r] + bval) * scl);
          }
        }
      } else {
#pragma unroll
        for (int r = 0; r < 4; ++r) of[(long)(mbase + r) * 1024 + c] = acc[mb][nb][r] + bo[c];
      }
    }
  }
}

// ---------------- flash attention: 4 waves/block, 128-row q-tile ----------------
// 512 blocks x 256 thr; CU-paired mirror balance: blocks id & id+256 share a CU,
// their qt sum to 15 -> per-CU k-tile work = 34, uniform.
__launch_bounds__(256, 2)
__global__ void k_attn(const unsigned short* __restrict__ Q,
                       const unsigned short* __restrict__ K,
                       const unsigned short* __restrict__ VT,
                       unsigned short* __restrict__ Z) {
  __shared__ __align__(16) unsigned short KV[2][2][64 * 64];  // [buf][K/V][64][64] swizzled
  __shared__ unsigned Zl[4][32 * 33];
  const int t = threadIdx.x;
  const int lane = t & 63, wv = t >> 6;
  const int l31 = lane & 31, h5 = lane >> 5;
  const int rl = lane >> 3, cl = lane & 7;
  const int id = blockIdx.x;                    // 512
  const int xcd = id & 7, j = id >> 3;
  const int bn = (j & 3) * 8 + xcd;             // 4 bn per XCD (K/V fits XCD L2)
  const int u = j >> 2;                         // [0,16)
  const int qt = (u < 8) ? (15 - u) : (u - 8);  // mirror pairs: qt(id)+qt(id+256)=15
  const int b = bn >> 4, n = bn & 15;
  const int r0w = qt * 128 + wv * 32;           // this wave's 32 q-rows
  const int qq = r0w + l31, qmax = r0w + 31;
  const int nkt = 2 * qt + 2;
  const unsigned short* Qb = Q + (long)bn * (2048 * 64);
  const unsigned short* Kb = K + (long)bn * (2048 * 64);
  const unsigned short* Vb = VT + (long)bn * (64 * 2048);
  unsigned* Zd = (unsigned*)Z;
  const int swl = (l31 & 7) << 4;

  auto stage = [&](int k0s, int nb) {           // wave stages 16 rows of K and of V
#pragma unroll
    for (int i = 0; i < 2; ++i) {
      int rbase = wv * 16 + i * 8;
      int r = rbase + rl;
      int cs = (cl ^ (r & 7)) * 8;              // pre-swizzled global source col
      __builtin_amdgcn_global_load_lds(
          (ga_u32*)(Kb + (long)(k0s + r) * 64 + cs),
          (lds_u32*)((lds_u16*)&KV[nb][0][0] + rbase * 64), 16, 0, 0);
      __builtin_amdgcn_global_load_lds(
          (ga_u32*)(Vb + (long)r * 2048 + k0s + cs),
          (lds_u32*)((lds_u16*)&KV[nb][1][0] + rbase * 64), 16, 0, 0);
    }
  };

  s16x8 qf[4];
#pragma unroll
  for (int hc = 0; hc < 4; ++hc)
    qf[hc] = *reinterpret_cast<const s16x8*>(Qb + (long)qq * 64 + hc * 16 + h5 * 8);

  f32x16 o0 = {}, o1 = {};                      // O^T[h][q]
  float mrun = -1e30f, lrun = 0.f;

  stage(0, 0);                                  // prologue: tile 0 -> buf 0

  for (int kt = 0; kt < nkt; ++kt) {
    const int k0 = kt << 6;
    const int cb = kt & 1;
    __syncthreads();                            // drains this tile's glds; frees other buf
    if (kt + 1 < nkt) stage((kt + 1) << 6, cb ^ 1);
    if (k0 > qmax) continue;                    // fully-masked tail tile (waves 0,1)

    const unsigned short* Ks = &KV[cb][0][0];
    const unsigned short* Vs = &KV[cb][1][0];
    const bool haveS1 = (k0 + 32 <= qmax);

    // S^T = K . Q^T
    f32x16 s0v = {}, s1v = {};
    __builtin_amdgcn_s_setprio(1);
#pragma unroll
    for (int hc = 0; hc < 4; ++hc) {
      int cbk = hc * 32 + h5 * 16;
      s16x8 kf0 = *reinterpret_cast<const s16x8*>(&Ks[l31 * 64 + ((cbk ^ swl) >> 1)]);
      s0v = __builtin_amdgcn_mfma_f32_32x32x16_bf16(kf0, qf[hc], s0v, 0, 0, 0);
    }
    if (haveS1)
#pragma unroll
      for (int hc = 0; hc < 4; ++hc) {
        int cbk = hc * 32 + h5 * 16;
        s16x8 kf1 = *reinterpret_cast<const s16x8*>(&Ks[(32 + l31) * 64 + ((cbk ^ swl) >> 1)]);
        s1v = __builtin_amdgcn_mfma_f32_32x32x16_bf16(kf1, qf[hc], s1v, 0, 0, 0);
      }
    __builtin_amdgcn_s_setprio(0);

    if (k0 + 63 > r0w) {                        // diagonal region: mask k > q
#pragma unroll
      for (int r = 0; r < 16; ++r) {
        int kA = k0 + (r & 3) + 8 * (r >> 2) + 4 * h5;
        if (kA > qq) s0v[r] = -1e30f;
        if (kA + 32 > qq) s1v[r] = -1e30f;
      }
    }

    float pmax = s0v[0];
#pragma unroll
    for (int r = 1; r < 16; ++r) pmax = fmaxf(pmax, s0v[r]);
    if (haveS1)
#pragma unroll
      for (int r = 0; r < 16; ++r) pmax = fmaxf(pmax, s1v[r]);
    pmax = fmaxf(pmax, __shfl_xor(pmax, 32));

    if (__any(pmax > mrun + 11.5f)) {           // defer-max (T13, log2 units)
      float mnew = fmaxf(mrun, pmax);
      float scl = __builtin_exp2f(mrun - mnew);
      lrun *= scl;
#pragma unroll
      for (int r = 0; r < 16; ++r) { o0[r] *= scl; o1[r] *= scl; }
      mrun = mnew;
    }
    float rs = 0.f;
#pragma unroll
    for (int r = 0; r < 16; ++r) { s0v[r] = __builtin_exp2f(s0v[r] - mrun); rs += s0v[r]; }
    if (haveS1)
#pragma unroll
      for (int r = 0; r < 16; ++r) { s1v[r] = __builtin_exp2f(s1v[r] - mrun); rs += s1v[r]; }
    rs += __shfl_xor(rs, 32);
    lrun += rs;

    // P -> bf16 B-frags via cvt_pk + permlane32_swap (T12)
    unsigned PK0[8], PK1[8];
#pragma unroll
    for (int m2 = 0; m2 < 8; ++m2) PK0[m2] = cvtpk(s0v[2 * m2], s0v[2 * m2 + 1]);
    if (haveS1)
#pragma unroll
      for (int m2 = 0; m2 < 8; ++m2) PK1[m2] = cvtpk(s1v[2 * m2], s1v[2 * m2 + 1]);

    __builtin_amdgcn_s_setprio(1);
#pragma unroll
    for (int c = 0; c < 4; ++c) {
      if (c >= 2 && !haveS1) break;             // uniform: skip zero k-half
      int base = (c & 1) * 4;
      unsigned x0 = (c >> 1) ? PK1[base + 0] : PK0[base + 0];
      unsigned y0 = (c >> 1) ? PK1[base + 2] : PK0[base + 2];
      unsigned x1 = (c >> 1) ? PK1[base + 1] : PK0[base + 1];
      unsigned y1 = (c >> 1) ? PK1[base + 3] : PK0[base + 3];
      pswap(x0, y0);
      pswap(x1, y1);
      union { s32x4 i; s16x8 h; } u2;
      u2.i = s32x4{(int)x0, (int)x1, (int)y0, (int)y1};
      int cbv = c * 32 + h5 * 16;
      s16x8 vf0 = *reinterpret_cast<const s16x8*>(&Vs[l31 * 64 + ((cbv ^ swl) >> 1)]);
      s16x8 vf1 = *reinterpret_cast<const s16x8*>(&Vs[(32 + l31) * 64 + ((cbv ^ swl) >> 1)]);
      o0 = __builtin_amdgcn_mfma_f32_32x32x16_bf16(vf0, u2.h, o0, 0, 0, 0);
      o1 = __builtin_amdgcn_mfma_f32_32x32x16_bf16(vf1, u2.h, o1, 0, 0, 0);
    }
    __builtin_amdgcn_s_setprio(0);
  }

  // epilogue: normalize, transpose O^T->O via wave-private LDS, coalesced store
  float inv = 1.0f / lrun;
#pragma unroll
  for (int hb = 0; hb < 2; ++hb) {
#pragma unroll
    for (int rp = 0; rp < 8; ++rp) {
      float vlo = (hb ? o1[2 * rp] : o0[2 * rp]) * inv;
      float vhi = (hb ? o1[2 * rp + 1] : o0[2 * rp + 1]) * inv;
      unsigned d = cvtpk(vlo, vhi);
      int col = 16 * hb + 4 * (rp >> 1) + 2 * h5 + (rp & 1);
      Zl[wv][l31 * 33 + col] = d;
    }
  }
  asm volatile("s_waitcnt lgkmcnt(0)" ::: "memory");   // wave-local LDS ordering
  const int qr = lane >> 1, cbs = (lane & 1) * 16;
  const long zb = ((long)(b * 2048 + r0w + qr)) * 512 + n * 32;   // dword index
#pragma unroll
  for (int c2 = 0; c2 < 4; ++c2) {
    u32x4 w4;
#pragma unroll
    for (int i2 = 0; i2 < 4; ++i2) w4[i2] = Zl[wv][qr * 33 + cbs + 4 * c2 + i2];
    *reinterpret_cast<u32x4*>(Zd + zb + cbs + 4 * c2) = w4;
  }
}

// ---------------- launcher ----------------
extern "C" void kernel_launch(void* const* d_in, const int* in_sizes, int n_in,
                              void* d_out, int out_size, void* d_ws, size_t ws_size,
                              hipStream_t stream) {
  const float* x  = (const float*)d_in[0];
  const float* wq = (const float*)d_in[1];
  const float* wk = (const float*)d_in[2];
  const float* wv = (const float*)d_in[3];
  const float* wo = (const float*)d_in[4];
  const float* bq = (const float*)d_in[5];
  const float* bk = (const float*)d_in[6];
  const float* bv = (const float*)d_in[7];
  const float* bo = (const float*)d_in[8];
  char* ws = (char*)d_ws;
  unsigned short* xb  = (unsigned short*)(ws);                  // 8 MiB  [4096][1024]
  unsigned short* Wt  = (unsigned short*)(ws + (8  << 20));     // 6 MiB  [3][16][64][1024]
  unsigned short* Wot = (unsigned short*)(ws + (14 << 20));     // 2 MiB  [1024][1024]
  unsigned short* Qw  = (unsigned short*)(ws + (16 << 20));     // 8 MiB  [2][16][2048][64]
  unsigned short* Kw  = (unsigned short*)(ws + (24 << 20));     // 8 MiB  [2][16][2048][64]
  unsigned short* Vw  = (unsigned short*)(ws + (32 << 20));     // 8 MiB  [2][16][64][2048] (V^T)
  unsigned short* Zw  = (unsigned short*)(ws + (40 << 20));     // 8 MiB  [4096][1024]
  float* out = (float*)d_out;

  k_prep<<<20480, 256, 0, stream>>>(x, wq, wk, wv, wo, xb, Wt, Wot);
  k_gemm<0, 128><<<dim3(24, 32), 256, 0, stream>>>(xb, Wt, bq, bk, bv, nullptr, Qw, Kw, Vw, nullptr);
  k_attn<<<512, 256, 0, stream>>>(Qw, Kw, Vw, Zw);
  k_gemm<1, 64><<<dim3(8, 64), 256, 0, stream>>>(Zw, Wot, nullptr, nullptr, nullptr, bo,
                                                 nullptr, nullptr, nullptr, out);
}